// Round 1
// baseline (3274.242 us; speedup 1.0000x reference)
//
#include <hip/hip_runtime.h>

#define N_NODES 150000
#define N_EDGES 2400000
#define N_GRAPHS 1024
#define F 32
#define EPSV 1e-5f

// ---------------------------------------------------------------------------
// K0: deg init to 1.0 (self-loop) + per-graph start offsets from sorted batch
// ---------------------------------------------------------------------------
__global__ void k_init(const int* __restrict__ batch, float* __restrict__ deg,
                       int* __restrict__ off) {
    int i = blockIdx.x * blockDim.x + threadIdx.x;
    if (i >= N_NODES) return;
    deg[i] = 1.0f;
    int b = batch[i];
    if (i == 0) {
        for (int g = 0; g <= b; ++g) off[g] = 0;
    } else {
        int pb = batch[i - 1];
        for (int g = pb + 1; g <= b; ++g) off[g] = i;
    }
    if (i == N_NODES - 1) {
        for (int g = b + 1; g <= N_GRAPHS; ++g) off[g] = N_NODES;
    }
}

// K1: degree accumulation over edges (A + I normalization)
__global__ void k_deg(const int* __restrict__ dst, float* __restrict__ deg) {
    int e = blockIdx.x * blockDim.x + threadIdx.x;
    if (e < N_EDGES) atomicAdd(&deg[dst[e]], 1.0f);
}

// K2: dinv_sqrt
__global__ void k_rsqrt(const float* __restrict__ deg, float* __restrict__ dinv) {
    int i = blockIdx.x * blockDim.x + threadIdx.x;
    if (i < N_NODES) dinv[i] = rsqrtf(deg[i]);
}

// ---------------------------------------------------------------------------
// K3: h = x @ W ; agg = dinv^2 * h + b   (self-loop term + bias pre-seeded)
// one thread per (node, feature)
// ---------------------------------------------------------------------------
template <int FIN>
__global__ void k_transform(const float* __restrict__ xin, const float* __restrict__ W,
                            const float* __restrict__ bias, const float* __restrict__ dinv,
                            float* __restrict__ h, float* __restrict__ agg) {
    int t = blockIdx.x * blockDim.x + threadIdx.x;
    if (t >= N_NODES * F) return;
    int n = t >> 5, f = t & 31;
    float acc = 0.f;
#pragma unroll
    for (int k = 0; k < FIN; ++k) acc += xin[n * FIN + k] * W[k * F + f];
    h[t] = acc;
    float di = dinv[n];
    agg[t] = di * di * acc + bias[f];
}

// ---------------------------------------------------------------------------
// K4: edge scatter: agg[dst] += h[src] * dinv[src]*dinv[dst]
// 8 threads per edge, each handles a float4 chunk (coalesced 128B row gather)
// ---------------------------------------------------------------------------
__global__ void k_edges(const int* __restrict__ src, const int* __restrict__ dst,
                        const float* __restrict__ dinv, const float* __restrict__ h,
                        float* __restrict__ agg) {
    int t = blockIdx.x * blockDim.x + threadIdx.x;
    if (t >= N_EDGES * 8) return;
    int e = t >> 3, c = t & 7;
    int s = src[e], d = dst[e];
    float co = dinv[s] * dinv[d];
    float4 hv = ((const float4*)h)[s * 8 + c];
    float* ap = agg + d * F + c * 4;
    atomicAdd(ap + 0, hv.x * co);
    atomicAdd(ap + 1, hv.y * co);
    atomicAdd(ap + 2, hv.z * co);
    atomicAdd(ap + 3, hv.w * co);
}

// ---------------------------------------------------------------------------
// K5: GraphNorm (+ residual + ReLU), block per graph (batch sorted).
// FINAL variant fuses mean-pool and the 32x3 output linear.
// block = 256 = 8 node-rows x 32 features.
// ---------------------------------------------------------------------------
template <bool RES, bool FINAL>
__global__ __launch_bounds__(256) void k_gn(
        const float* __restrict__ agg, const float* __restrict__ res,
        const int* __restrict__ off,
        const float* __restrict__ gw, const float* __restrict__ gb,
        const float* __restrict__ gms,
        const float* __restrict__ lin_w, const float* __restrict__ lin_b,
        float* __restrict__ outp) {
    __shared__ float red[256];
    __shared__ float mean_s[F], rstd_s[F], pooled_s[F];
    int g = blockIdx.x;
    int i0 = off[g], i1 = off[g + 1];
    float cnt = (float)(i1 - i0);
    int t = threadIdx.x;
    int f = t & 31, r0 = t >> 5;
    float w = gw[f], bb = gb[f], ms = gms[f];

    // pass 1: mean
    float s = 0.f;
    for (int n = i0 + r0; n < i1; n += 8) s += agg[n * F + f];
    red[t] = s; __syncthreads();
    if (t < 128) red[t] += red[t + 128]; __syncthreads();
    if (t < 64)  red[t] += red[t + 64];  __syncthreads();
    if (t < 32) { red[t] += red[t + 32]; mean_s[t] = red[t] / cnt; }
    __syncthreads();

    // pass 2: variance of centered values
    float sq = 0.f;
    for (int n = i0 + r0; n < i1; n += 8) {
        float c = agg[n * F + f] - ms * mean_s[f];
        sq += c * c;
    }
    red[t] = sq; __syncthreads();
    if (t < 128) red[t] += red[t + 128]; __syncthreads();
    if (t < 64)  red[t] += red[t + 64];  __syncthreads();
    if (t < 32) { red[t] += red[t + 32]; rstd_s[t] = rsqrtf(red[t] / cnt + EPSV); }
    __syncthreads();

    // pass 3: normalize (+residual) + relu; write or pool
    float ps = 0.f;
    for (int n = i0 + r0; n < i1; n += 8) {
        float c = agg[n * F + f] - ms * mean_s[f];
        float y = w * c * rstd_s[f] + bb;
        if (RES) y += res[n * F + f];
        y = fmaxf(y, 0.f);
        if (!FINAL) outp[n * F + f] = y;
        else        ps += y;
    }
    if (FINAL) {
        __syncthreads();
        red[t] = ps; __syncthreads();
        if (t < 128) red[t] += red[t + 128]; __syncthreads();
        if (t < 64)  red[t] += red[t + 64];  __syncthreads();
        if (t < 32) { red[t] += red[t + 32]; pooled_s[t] = red[t] / cnt; }
        __syncthreads();
        if (t < 3) {
            float o = lin_b[t];
#pragma unroll
            for (int f2 = 0; f2 < F; ++f2) o += pooled_s[f2] * lin_w[f2 * 3 + t];
            outp[g * 3 + t] = o;
        }
    }
}

// ---------------------------------------------------------------------------
extern "C" void kernel_launch(void* const* d_in, const int* in_sizes, int n_in,
                              void* d_out, int out_size, void* d_ws, size_t ws_size,
                              hipStream_t stream) {
    const float* x      = (const float*)d_in[0];
    const int*   ei     = (const int*)d_in[1];
    const int*   batch  = (const int*)d_in[2];
    const float* W1     = (const float*)d_in[3];
    const float* b1     = (const float*)d_in[4];
    const float* gn1w   = (const float*)d_in[5];
    const float* gn1b   = (const float*)d_in[6];
    const float* gn1ms  = (const float*)d_in[7];
    const float* W2     = (const float*)d_in[8];
    const float* b2     = (const float*)d_in[9];
    const float* gn2w   = (const float*)d_in[10];
    const float* gn2b   = (const float*)d_in[11];
    const float* gn2ms  = (const float*)d_in[12];
    const float* W3     = (const float*)d_in[13];
    const float* b3     = (const float*)d_in[14];
    const float* gn3w   = (const float*)d_in[15];
    const float* gn3b   = (const float*)d_in[16];
    const float* gn3ms  = (const float*)d_in[17];
    const float* lin_w  = (const float*)d_in[18];
    const float* lin_b  = (const float*)d_in[19];
    float* out = (float*)d_out;

    const int* srcp = ei;
    const int* dstp = ei + N_EDGES;

    // workspace carve-up (512B aligned)
    char* ws = (char*)d_ws;
    size_t p = 0;
    auto alloc = [&](size_t bytes) {
        size_t r = p; p += (bytes + 511) & ~(size_t)511; return r;
    };
    int*   off  = (int*)  (ws + alloc(sizeof(int) * (N_GRAPHS + 1)));
    float* deg  = (float*)(ws + alloc(sizeof(float) * N_NODES));
    float* dinv = (float*)(ws + alloc(sizeof(float) * N_NODES));
    float* A    = (float*)(ws + alloc(sizeof(float) * N_NODES * F));
    float* B    = (float*)(ws + alloc(sizeof(float) * N_NODES * F));
    float* C    = (float*)(ws + alloc(sizeof(float) * N_NODES * F));
    (void)ws_size; (void)n_in; (void)in_sizes; (void)out_size;

    const int TB = 256;
    dim3 blk(TB);

    k_init<<<(N_NODES + TB - 1) / TB, blk, 0, stream>>>(batch, deg, off);
    k_deg<<<(N_EDGES + TB - 1) / TB, blk, 0, stream>>>(dstp, deg);
    k_rsqrt<<<(N_NODES + TB - 1) / TB, blk, 0, stream>>>(deg, dinv);

    int tgrid = (N_NODES * F + TB - 1) / TB;
    int egrid = (N_EDGES * 8 + TB - 1) / TB;

    // layer 1: x -> h=A, agg=B ; GN -> x1=C
    k_transform<3><<<tgrid, blk, 0, stream>>>(x, W1, b1, dinv, A, B);
    k_edges<<<egrid, blk, 0, stream>>>(srcp, dstp, dinv, A, B);
    k_gn<false, false><<<N_GRAPHS, blk, 0, stream>>>(B, nullptr, off, gn1w, gn1b, gn1ms,
                                                     nullptr, nullptr, C);

    // layer 2: x1=C -> h=A, agg=B ; GN + residual(C) -> x2=A
    k_transform<32><<<tgrid, blk, 0, stream>>>(C, W2, b2, dinv, A, B);
    k_edges<<<egrid, blk, 0, stream>>>(srcp, dstp, dinv, A, B);
    k_gn<true, false><<<N_GRAPHS, blk, 0, stream>>>(B, C, off, gn2w, gn2b, gn2ms,
                                                    nullptr, nullptr, A);

    // layer 3: x2=A -> h=C, agg=B ; GN + residual(A) + pool + linear -> out
    k_transform<32><<<tgrid, blk, 0, stream>>>(A, W3, b3, dinv, C, B);
    k_edges<<<egrid, blk, 0, stream>>>(srcp, dstp, dinv, C, B);
    k_gn<true, true><<<N_GRAPHS, blk, 0, stream>>>(B, A, off, gn3w, gn3b, gn3ms,
                                                   lin_w, lin_b, out);
}

// Round 2
// 613.316 us; speedup vs baseline: 5.3386x; 5.3386x over previous
//
#include <hip/hip_runtime.h>

#define N_NODES 150000
#define N_EDGES 2400000
#define N_GRAPHS 1024
#define F 32
#define EPSV 1e-5f

#define SCAN_T 256
#define SCAN_ITEMS 4
#define SCAN_BLK (SCAN_T * SCAN_ITEMS)                  // 1024
#define N_SBLK ((N_NODES + SCAN_BLK - 1) / SCAN_BLK)    // 147

// ---------------------------------------------------------------------------
// K0: per-graph start offsets from sorted batch; zero the degree histogram
// ---------------------------------------------------------------------------
__global__ void k_init(const int* __restrict__ batch, int* __restrict__ cnt,
                       int* __restrict__ off) {
    int i = blockIdx.x * blockDim.x + threadIdx.x;
    if (i >= N_NODES) return;
    cnt[i] = 0;
    int b = batch[i];
    if (i == 0) {
        for (int g = 0; g <= b; ++g) off[g] = 0;
    } else {
        int pb = batch[i - 1];
        for (int g = pb + 1; g <= b; ++g) off[g] = i;
    }
    if (i == N_NODES - 1) {
        for (int g = b + 1; g <= N_GRAPHS; ++g) off[g] = N_NODES;
    }
}

// K1: in-degree histogram (int)
__global__ void k_hist(const int* __restrict__ dst, int* __restrict__ cnt) {
    int e = blockIdx.x * blockDim.x + threadIdx.x;
    if (e < N_EDGES) atomicAdd(&cnt[dst[e]], 1);
}

// K2a/b/c: exclusive scan of cnt -> rowptr
__global__ void k_scan1(const int* __restrict__ cnt, int* __restrict__ rowptr,
                        int* __restrict__ bsum) {
    __shared__ int sh[SCAN_T];
    int b = blockIdx.x, t = threadIdx.x;
    int base = b * SCAN_BLK + t * SCAN_ITEMS;
    int v[SCAN_ITEMS];
    int s = 0;
#pragma unroll
    for (int k = 0; k < SCAN_ITEMS; ++k) {
        int i = base + k;
        v[k] = (i < N_NODES) ? cnt[i] : 0;
        s += v[k];
    }
    sh[t] = s;
    __syncthreads();
    for (int o = 1; o < SCAN_T; o <<= 1) {
        int x = (t >= o) ? sh[t - o] : 0;
        __syncthreads();
        sh[t] += x;
        __syncthreads();
    }
    int run = sh[t] - s;  // exclusive prefix of this thread within block
    if (t == SCAN_T - 1) bsum[b] = sh[t];
#pragma unroll
    for (int k = 0; k < SCAN_ITEMS; ++k) {
        int i = base + k;
        if (i < N_NODES) rowptr[i] = run;
        run += v[k];
    }
}

__global__ void k_scan2(int* __restrict__ bsum) {
    __shared__ int sh[SCAN_T];
    int t = threadIdx.x;
    int v = (t < N_SBLK) ? bsum[t] : 0;
    sh[t] = v;
    __syncthreads();
    for (int o = 1; o < SCAN_T; o <<= 1) {
        int x = (t >= o) ? sh[t - o] : 0;
        __syncthreads();
        sh[t] += x;
        __syncthreads();
    }
    if (t < N_SBLK) bsum[t] = sh[t] - v;  // exclusive
}

__global__ void k_scan3(int* __restrict__ rowptr, const int* __restrict__ bsum) {
    int i = blockIdx.x * blockDim.x + threadIdx.x;
    if (i < N_NODES) rowptr[i] += bsum[i >> 10];
    if (i == 0) rowptr[N_NODES] = N_EDGES;
}

// K3: dinv = rsqrt(deg) with deg = cnt + 1 (self loop)
__global__ void k_dinv(const int* __restrict__ cnt, float* __restrict__ dinv) {
    int i = blockIdx.x * blockDim.x + threadIdx.x;
    if (i < N_NODES) dinv[i] = rsqrtf((float)cnt[i] + 1.0f);
}

// K4: fill CSR (consumes cnt via countdown)
__global__ void k_fill(const int* __restrict__ src, const int* __restrict__ dst,
                       int* __restrict__ cnt, const int* __restrict__ rowptr,
                       int* __restrict__ csr) {
    int e = blockIdx.x * blockDim.x + threadIdx.x;
    if (e >= N_EDGES) return;
    int d = dst[e];
    int pos = atomicSub(&cnt[d], 1) - 1;
    csr[rowptr[d] + pos] = src[e];
}

// ---------------------------------------------------------------------------
// K5a: layer-1 fused aggregate(3-wide) + transform(3->32) + bias
// 8 threads/node; each redundantly accumulates full 3-wide z (broadcast loads),
// then emits its float4 chunk of y = z @ W + b.
// ---------------------------------------------------------------------------
__global__ __launch_bounds__(256) void k_gat3(
        const float* __restrict__ x, const int* __restrict__ csr,
        const int* __restrict__ rowptr, const float* __restrict__ dinv,
        const float* __restrict__ W, const float* __restrict__ bias,
        float* __restrict__ y) {
    int gid = blockIdx.x * 256 + threadIdx.x;
    int n = gid >> 3, c = gid & 7;
    if (n >= N_NODES) return;
    float dd = dinv[n];
    float sl = dd * dd;
    float z0 = x[n * 3 + 0] * sl, z1 = x[n * 3 + 1] * sl, z2 = x[n * 3 + 2] * sl;
    int e0 = rowptr[n], e1 = rowptr[n + 1];
    for (int e = e0; e < e1; ++e) {
        int s = csr[e];
        float co = dinv[s] * dd;
        z0 += co * x[s * 3 + 0];
        z1 += co * x[s * 3 + 1];
        z2 += co * x[s * 3 + 2];
    }
    float4 w0 = ((const float4*)(W + 0 * F))[c];
    float4 w1 = ((const float4*)(W + 1 * F))[c];
    float4 w2 = ((const float4*)(W + 2 * F))[c];
    float4 o  = ((const float4*)bias)[c];
    o.x += z0 * w0.x + z1 * w1.x + z2 * w2.x;
    o.y += z0 * w0.y + z1 * w1.y + z2 * w2.y;
    o.z += z0 * w0.z + z1 * w1.z + z2 * w2.z;
    o.w += z0 * w0.w + z1 * w1.w + z2 * w2.w;
    ((float4*)y)[n * 8 + c] = o;
}

// ---------------------------------------------------------------------------
// K5b: fused aggregate(32-wide) + transform(32->32) + bias.
// 8 threads/node gather float4 chunks of z; LDS exchange (row stride 36 floats
// -> conflict-free); then y[n, c*4..] = b + z-row @ W columns.
// ---------------------------------------------------------------------------
__global__ __launch_bounds__(256) void k_gat32(
        const float* __restrict__ x, const int* __restrict__ csr,
        const int* __restrict__ rowptr, const float* __restrict__ dinv,
        const float* __restrict__ W, const float* __restrict__ bias,
        float* __restrict__ y) {
    __shared__ float Ws[F * F];     // 4 KB
    __shared__ float bs[F];
    __shared__ float Zs[32 * 36];   // 32 local nodes, padded stride
    int t = threadIdx.x;
    ((float4*)Ws)[t] = ((const float4*)W)[t];  // 256 * 16B = 4 KB exactly
    if (t < F) bs[t] = bias[t];
    __syncthreads();

    int gid = blockIdx.x * 256 + t;
    int n = gid >> 3, c = gid & 7, ln = t >> 3;
    float4 acc = {0.f, 0.f, 0.f, 0.f};
    if (n < N_NODES) {
        float dd = dinv[n];
        const float4* x4 = (const float4*)x;
        acc = x4[n * 8 + c];
        float sl = dd * dd;
        acc.x *= sl; acc.y *= sl; acc.z *= sl; acc.w *= sl;
        int e0 = rowptr[n], e1 = rowptr[n + 1];
        for (int e = e0; e < e1; ++e) {
            int s = csr[e];
            float co = dinv[s] * dd;
            float4 hv = x4[s * 8 + c];
            acc.x += co * hv.x; acc.y += co * hv.y;
            acc.z += co * hv.z; acc.w += co * hv.w;
        }
    }
    *(float4*)&Zs[ln * 36 + c * 4] = acc;
    __syncthreads();

    if (n < N_NODES) {
        const float* zrow = &Zs[ln * 36];
        float4 o = ((const float4*)bs)[c];
#pragma unroll
        for (int k = 0; k < F; ++k) {
            float zk = zrow[k];
            float4 w = ((const float4*)&Ws[k * F])[c];
            o.x += zk * w.x; o.y += zk * w.y; o.z += zk * w.z; o.w += zk * w.w;
        }
        ((float4*)y)[n * 8 + c] = o;
    }
}

// ---------------------------------------------------------------------------
// K6: GraphNorm (+ residual + ReLU), block per graph. In-place capable
// (outp may alias agg) -> no __restrict__ on those. FINAL fuses pool+linear.
// ---------------------------------------------------------------------------
template <bool RES, bool FINAL>
__global__ __launch_bounds__(256) void k_gn(
        const float* agg, const float* res, const int* __restrict__ off,
        const float* __restrict__ gw, const float* __restrict__ gb,
        const float* __restrict__ gms,
        const float* __restrict__ lin_w, const float* __restrict__ lin_b,
        float* outp) {
    __shared__ float red[256];
    __shared__ float mean_s[F], rstd_s[F], pooled_s[F];
    int g = blockIdx.x;
    int i0 = off[g], i1 = off[g + 1];
    float cnt = (float)(i1 - i0);
    int t = threadIdx.x;
    int f = t & 31, r0 = t >> 5;
    float w = gw[f], bb = gb[f], ms = gms[f];

    float s = 0.f;
    for (int n = i0 + r0; n < i1; n += 8) s += agg[n * F + f];
    red[t] = s; __syncthreads();
    if (t < 128) red[t] += red[t + 128]; __syncthreads();
    if (t < 64)  red[t] += red[t + 64];  __syncthreads();
    if (t < 32) { red[t] += red[t + 32]; mean_s[t] = red[t] / cnt; }
    __syncthreads();

    float sq = 0.f;
    for (int n = i0 + r0; n < i1; n += 8) {
        float c = agg[n * F + f] - ms * mean_s[f];
        sq += c * c;
    }
    red[t] = sq; __syncthreads();
    if (t < 128) red[t] += red[t + 128]; __syncthreads();
    if (t < 64)  red[t] += red[t + 64];  __syncthreads();
    if (t < 32) { red[t] += red[t + 32]; rstd_s[t] = rsqrtf(red[t] / cnt + EPSV); }
    __syncthreads();

    float ps = 0.f;
    for (int n = i0 + r0; n < i1; n += 8) {
        float c = agg[n * F + f] - ms * mean_s[f];
        float y = w * c * rstd_s[f] + bb;
        if (RES) y += res[n * F + f];
        y = fmaxf(y, 0.f);
        if (!FINAL) outp[n * F + f] = y;
        else        ps += y;
    }
    if (FINAL) {
        __syncthreads();
        red[t] = ps; __syncthreads();
        if (t < 128) red[t] += red[t + 128]; __syncthreads();
        if (t < 64)  red[t] += red[t + 64];  __syncthreads();
        if (t < 32) { red[t] += red[t + 32]; pooled_s[t] = red[t] / cnt; }
        __syncthreads();
        if (t < 3) {
            float o = lin_b[t];
#pragma unroll
            for (int f2 = 0; f2 < F; ++f2) o += pooled_s[f2] * lin_w[f2 * 3 + t];
            outp[g * 3 + t] = o;
        }
    }
}

// ---------------------------------------------------------------------------
extern "C" void kernel_launch(void* const* d_in, const int* in_sizes, int n_in,
                              void* d_out, int out_size, void* d_ws, size_t ws_size,
                              hipStream_t stream) {
    const float* x      = (const float*)d_in[0];
    const int*   ei     = (const int*)d_in[1];
    const int*   batch  = (const int*)d_in[2];
    const float* W1     = (const float*)d_in[3];
    const float* b1     = (const float*)d_in[4];
    const float* gn1w   = (const float*)d_in[5];
    const float* gn1b   = (const float*)d_in[6];
    const float* gn1ms  = (const float*)d_in[7];
    const float* W2     = (const float*)d_in[8];
    const float* b2     = (const float*)d_in[9];
    const float* gn2w   = (const float*)d_in[10];
    const float* gn2b   = (const float*)d_in[11];
    const float* gn2ms  = (const float*)d_in[12];
    const float* W3     = (const float*)d_in[13];
    const float* b3     = (const float*)d_in[14];
    const float* gn3w   = (const float*)d_in[15];
    const float* gn3b   = (const float*)d_in[16];
    const float* gn3ms  = (const float*)d_in[17];
    const float* lin_w  = (const float*)d_in[18];
    const float* lin_b  = (const float*)d_in[19];
    float* out = (float*)d_out;

    const int* srcp = ei;
    const int* dstp = ei + N_EDGES;

    char* ws = (char*)d_ws;
    size_t p = 0;
    auto alloc = [&](size_t bytes) {
        size_t r = p; p += (bytes + 511) & ~(size_t)511; return r;
    };
    int*   off    = (int*)  (ws + alloc(sizeof(int) * (N_GRAPHS + 1)));
    int*   cnt    = (int*)  (ws + alloc(sizeof(int) * N_NODES));
    int*   rowptr = (int*)  (ws + alloc(sizeof(int) * (N_NODES + 1)));
    int*   bsum   = (int*)  (ws + alloc(sizeof(int) * N_SBLK));
    float* dinv   = (float*)(ws + alloc(sizeof(float) * N_NODES));
    int*   csr    = (int*)  (ws + alloc(sizeof(int) * N_EDGES));
    float* A      = (float*)(ws + alloc(sizeof(float) * N_NODES * F));
    float* B      = (float*)(ws + alloc(sizeof(float) * N_NODES * F));
    (void)ws_size; (void)n_in; (void)in_sizes; (void)out_size;

    const int TB = 256;
    dim3 blk(TB);
    int ngrid = (N_NODES + TB - 1) / TB;
    int egrid = (N_EDGES + TB - 1) / TB;
    int ggrid = (N_NODES * 8 + TB - 1) / TB;

    // CSR build + normalization constants
    k_init <<<ngrid, blk, 0, stream>>>(batch, cnt, off);
    k_hist <<<egrid, blk, 0, stream>>>(dstp, cnt);
    k_scan1<<<N_SBLK, SCAN_T, 0, stream>>>(cnt, rowptr, bsum);
    k_scan2<<<1, SCAN_T, 0, stream>>>(bsum);
    k_scan3<<<ngrid, blk, 0, stream>>>(rowptr, bsum);
    k_dinv <<<ngrid, blk, 0, stream>>>(cnt, dinv);
    k_fill <<<egrid, blk, 0, stream>>>(srcp, dstp, cnt, rowptr, csr);

    // layer 1: x(3w) -> y1=A ; GN in-place -> x1=A
    k_gat3 <<<ggrid, blk, 0, stream>>>(x, csr, rowptr, dinv, W1, b1, A);
    k_gn<false, false><<<N_GRAPHS, blk, 0, stream>>>(A, nullptr, off, gn1w, gn1b, gn1ms,
                                                     nullptr, nullptr, A);

    // layer 2: x1=A -> y2=B ; GN + res(A) in-place -> x2=B
    k_gat32<<<ggrid, blk, 0, stream>>>(A, csr, rowptr, dinv, W2, b2, B);
    k_gn<true, false><<<N_GRAPHS, blk, 0, stream>>>(B, A, off, gn2w, gn2b, gn2ms,
                                                    nullptr, nullptr, B);

    // layer 3: x2=B -> y3=A ; GN + res(B) + pool + linear -> out
    k_gat32<<<ggrid, blk, 0, stream>>>(B, csr, rowptr, dinv, W3, b3, A);
    k_gn<true, true><<<N_GRAPHS, blk, 0, stream>>>(A, B, off, gn3w, gn3b, gn3ms,
                                                   lin_w, lin_b, out);
}

// Round 3
// 402.346 us; speedup vs baseline: 8.1379x; 1.5243x over previous
//
#include <hip/hip_runtime.h>

#define N_NODES 150000
#define N_EDGES 2400000
#define N_GRAPHS 1024
#define F 32
#define EPSV 1e-5f

#define BS 256                                   // nodes per dst-bucket
#define NB ((N_NODES + BS - 1) / BS)             // 586 buckets
#define EB 4096                                  // edges per binning block
#define NEB ((N_EDGES + EB - 1) / EB)            // 586 blocks
#define EPT (EB / 256)                           // 16 edges per thread

// ---------------------------------------------------------------------------
// K0: per-graph start offsets from sorted batch; zero bucket histogram;
// seed rowptr[N_NODES]
// ---------------------------------------------------------------------------
__global__ void k_init(const int* __restrict__ batch, int* __restrict__ bucketCnt,
                       int* __restrict__ off, int* __restrict__ rowptr) {
    int i = blockIdx.x * blockDim.x + threadIdx.x;
    if (i >= N_NODES) return;
    if (i < NB) bucketCnt[i] = 0;
    if (i == 0) rowptr[N_NODES] = N_EDGES;
    int b = batch[i];
    if (i == 0) {
        for (int g = 0; g <= b; ++g) off[g] = 0;
    } else {
        int pb = batch[i - 1];
        for (int g = pb + 1; g <= b; ++g) off[g] = i;
    }
    if (i == N_NODES - 1) {
        for (int g = b + 1; g <= N_GRAPHS; ++g) off[g] = N_NODES;
    }
}

// ---------------------------------------------------------------------------
// K1: bucket histogram (LDS-aggregated -> 586 global atomics per block)
// ---------------------------------------------------------------------------
__global__ __launch_bounds__(256) void k_bhist(const int* __restrict__ dst,
                                               int* __restrict__ bucketCnt) {
    __shared__ int h[NB];
    int t = threadIdx.x;
    for (int b = t; b < NB; b += 256) h[b] = 0;
    __syncthreads();
    int base = blockIdx.x * EB + t;
#pragma unroll
    for (int k = 0; k < EPT; ++k) {
        int e = base + k * 256;
        if (e < N_EDGES) atomicAdd(&h[dst[e] >> 8], 1);
    }
    __syncthreads();
    for (int b = t; b < NB; b += 256) {
        int c = h[b];
        if (c) atomicAdd(&bucketCnt[b], c);
    }
}

// ---------------------------------------------------------------------------
// K2: exclusive scan of 586 bucket counts (single block) -> off + cursors
// ---------------------------------------------------------------------------
__global__ __launch_bounds__(256) void k_bscan(const int* __restrict__ bucketCnt,
                                               int* __restrict__ bucketOff,
                                               int* __restrict__ bucketCur) {
    __shared__ int sc[256];
    int t = threadIdx.x;
    int v[3];
    int s = 0;
#pragma unroll
    for (int k = 0; k < 3; ++k) {
        int i = t * 3 + k;
        v[k] = (i < NB) ? bucketCnt[i] : 0;
        s += v[k];
    }
    sc[t] = s;
    __syncthreads();
    for (int o = 1; o < 256; o <<= 1) {
        int x = (t >= o) ? sc[t - o] : 0;
        __syncthreads();
        sc[t] += x;
        __syncthreads();
    }
    int run = sc[t] - s;
#pragma unroll
    for (int k = 0; k < 3; ++k) {
        int i = t * 3 + k;
        if (i < NB) { bucketOff[i] = run; bucketCur[i] = run; }
        run += v[k];
    }
    if (t == 0) bucketOff[NB] = N_EDGES;
}

// ---------------------------------------------------------------------------
// K3: bin edges into buckets. Packed key = (localdst << 18) | src  (26 bits).
// LDS rank + one global atomicAdd per (block,bucket); writes land in ~7-entry
// contiguous runs per bucket.
// ---------------------------------------------------------------------------
__global__ __launch_bounds__(256) void k_bin(const int* __restrict__ src,
                                             const int* __restrict__ dst,
                                             int* __restrict__ bucketCur,
                                             unsigned int* __restrict__ binned) {
    __shared__ int h[NB];
    __shared__ int gb[NB];
    int t = threadIdx.x;
    for (int b = t; b < NB; b += 256) h[b] = 0;
    __syncthreads();
    int base = blockIdx.x * EB + t;
    unsigned int key[EPT];
    int rk[EPT], bk[EPT];
#pragma unroll
    for (int k = 0; k < EPT; ++k) {
        int e = base + k * 256;
        if (e < N_EDGES) {
            int d = dst[e];
            int b = d >> 8;
            bk[k] = b;
            key[k] = ((unsigned int)(d & 255) << 18) | (unsigned int)src[e];
            rk[k] = atomicAdd(&h[b], 1);
        } else {
            bk[k] = -1;
        }
    }
    __syncthreads();
    for (int b = t; b < NB; b += 256) {
        int c = h[b];
        gb[b] = c ? atomicAdd(&bucketCur[b], c) : 0;
    }
    __syncthreads();
#pragma unroll
    for (int k = 0; k < EPT; ++k)
        if (bk[k] >= 0) binned[gb[bk[k]] + rk[k]] = key[k];
}

// ---------------------------------------------------------------------------
// K4: per-bucket CSR finalize: LDS histogram + scan -> rowptr, dinv (fused),
// csr fill with scatters confined to this bucket's contiguous region.
// ---------------------------------------------------------------------------
__global__ __launch_bounds__(256) void k_csr(const unsigned int* __restrict__ binned,
                                             const int* __restrict__ bucketOff,
                                             int* __restrict__ rowptr,
                                             float* __restrict__ dinv,
                                             int* __restrict__ csr) {
    __shared__ int lcnt[256];
    __shared__ int lpre[256];
    __shared__ int sc[256];
    int b = blockIdx.x, t = threadIdx.x;
    int e0 = bucketOff[b], e1 = bucketOff[b + 1];
    lcnt[t] = 0;
    __syncthreads();
    for (int e = e0 + t; e < e1; e += 256)
        atomicAdd(&lcnt[binned[e] >> 18], 1);
    __syncthreads();
    int v = lcnt[t];
    sc[t] = v;
    __syncthreads();
    for (int o = 1; o < 256; o <<= 1) {
        int x = (t >= o) ? sc[t - o] : 0;
        __syncthreads();
        sc[t] += x;
        __syncthreads();
    }
    int excl = sc[t] - v;
    lpre[t] = excl;
    int gnode = b * BS + t;
    if (gnode < N_NODES) {
        rowptr[gnode] = e0 + excl;
        dinv[gnode] = rsqrtf((float)v + 1.0f);
    }
    lcnt[t] = 0;
    __syncthreads();
    for (int e = e0 + t; e < e1; e += 256) {
        unsigned int key = binned[e];
        int ld = key >> 18;
        int pos = atomicAdd(&lcnt[ld], 1);
        csr[e0 + lpre[ld] + pos] = (int)(key & 0x3FFFFu);
    }
}

// ---------------------------------------------------------------------------
// K5a: layer-1 fused aggregate(3-wide) + transform(3->32) + bias
// ---------------------------------------------------------------------------
__global__ __launch_bounds__(256) void k_gat3(
        const float* __restrict__ x, const int* __restrict__ csr,
        const int* __restrict__ rowptr, const float* __restrict__ dinv,
        const float* __restrict__ W, const float* __restrict__ bias,
        float* __restrict__ y) {
    int gid = blockIdx.x * 256 + threadIdx.x;
    int n = gid >> 3, c = gid & 7;
    if (n >= N_NODES) return;
    float dd = dinv[n];
    float sl = dd * dd;
    float z0 = x[n * 3 + 0] * sl, z1 = x[n * 3 + 1] * sl, z2 = x[n * 3 + 2] * sl;
    int e0 = rowptr[n], e1 = rowptr[n + 1];
    for (int e = e0; e < e1; ++e) {
        int s = csr[e];
        float co = dinv[s] * dd;
        z0 += co * x[s * 3 + 0];
        z1 += co * x[s * 3 + 1];
        z2 += co * x[s * 3 + 2];
    }
    float4 w0 = ((const float4*)(W + 0 * F))[c];
    float4 w1 = ((const float4*)(W + 1 * F))[c];
    float4 w2 = ((const float4*)(W + 2 * F))[c];
    float4 o  = ((const float4*)bias)[c];
    o.x += z0 * w0.x + z1 * w1.x + z2 * w2.x;
    o.y += z0 * w0.y + z1 * w1.y + z2 * w2.y;
    o.z += z0 * w0.z + z1 * w1.z + z2 * w2.z;
    o.w += z0 * w0.w + z1 * w1.w + z2 * w2.w;
    ((float4*)y)[n * 8 + c] = o;
}

// ---------------------------------------------------------------------------
// K5b: fused aggregate(32-wide) + transform(32->32) + bias
// ---------------------------------------------------------------------------
__global__ __launch_bounds__(256) void k_gat32(
        const float* __restrict__ x, const int* __restrict__ csr,
        const int* __restrict__ rowptr, const float* __restrict__ dinv,
        const float* __restrict__ W, const float* __restrict__ bias,
        float* __restrict__ y) {
    __shared__ float Ws[F * F];
    __shared__ float bs[F];
    __shared__ float Zs[32 * 36];
    int t = threadIdx.x;
    ((float4*)Ws)[t] = ((const float4*)W)[t];
    if (t < F) bs[t] = bias[t];
    __syncthreads();

    int gid = blockIdx.x * 256 + t;
    int n = gid >> 3, c = gid & 7, ln = t >> 3;
    float4 acc = {0.f, 0.f, 0.f, 0.f};
    if (n < N_NODES) {
        float dd = dinv[n];
        const float4* x4 = (const float4*)x;
        acc = x4[n * 8 + c];
        float sl = dd * dd;
        acc.x *= sl; acc.y *= sl; acc.z *= sl; acc.w *= sl;
        int e0 = rowptr[n], e1 = rowptr[n + 1];
        for (int e = e0; e < e1; ++e) {
            int s = csr[e];
            float co = dinv[s] * dd;
            float4 hv = x4[s * 8 + c];
            acc.x += co * hv.x; acc.y += co * hv.y;
            acc.z += co * hv.z; acc.w += co * hv.w;
        }
    }
    *(float4*)&Zs[ln * 36 + c * 4] = acc;
    __syncthreads();

    if (n < N_NODES) {
        const float* zrow = &Zs[ln * 36];
        float4 o = ((const float4*)bs)[c];
#pragma unroll
        for (int k = 0; k < F; ++k) {
            float zk = zrow[k];
            float4 w = ((const float4*)&Ws[k * F])[c];
            o.x += zk * w.x; o.y += zk * w.y; o.z += zk * w.z; o.w += zk * w.w;
        }
        ((float4*)y)[n * 8 + c] = o;
    }
}

// ---------------------------------------------------------------------------
// K6: GraphNorm (+ residual + ReLU), block per graph; in-place capable;
// FINAL fuses mean-pool + 32x3 linear.
// ---------------------------------------------------------------------------
template <bool RES, bool FINAL>
__global__ __launch_bounds__(256) void k_gn(
        const float* agg, const float* res, const int* __restrict__ off,
        const float* __restrict__ gw, const float* __restrict__ gb,
        const float* __restrict__ gms,
        const float* __restrict__ lin_w, const float* __restrict__ lin_b,
        float* outp) {
    __shared__ float red[256];
    __shared__ float mean_s[F], rstd_s[F], pooled_s[F];
    int g = blockIdx.x;
    int i0 = off[g], i1 = off[g + 1];
    float cnt = (float)(i1 - i0);
    int t = threadIdx.x;
    int f = t & 31, r0 = t >> 5;
    float w = gw[f], bb = gb[f], ms = gms[f];

    float s = 0.f;
    for (int n = i0 + r0; n < i1; n += 8) s += agg[n * F + f];
    red[t] = s; __syncthreads();
    if (t < 128) red[t] += red[t + 128]; __syncthreads();
    if (t < 64)  red[t] += red[t + 64];  __syncthreads();
    if (t < 32) { red[t] += red[t + 32]; mean_s[t] = red[t] / cnt; }
    __syncthreads();

    float sq = 0.f;
    for (int n = i0 + r0; n < i1; n += 8) {
        float c = agg[n * F + f] - ms * mean_s[f];
        sq += c * c;
    }
    red[t] = sq; __syncthreads();
    if (t < 128) red[t] += red[t + 128]; __syncthreads();
    if (t < 64)  red[t] += red[t + 64];  __syncthreads();
    if (t < 32) { red[t] += red[t + 32]; rstd_s[t] = rsqrtf(red[t] / cnt + EPSV); }
    __syncthreads();

    float ps = 0.f;
    for (int n = i0 + r0; n < i1; n += 8) {
        float c = agg[n * F + f] - ms * mean_s[f];
        float y = w * c * rstd_s[f] + bb;
        if (RES) y += res[n * F + f];
        y = fmaxf(y, 0.f);
        if (!FINAL) outp[n * F + f] = y;
        else        ps += y;
    }
    if (FINAL) {
        __syncthreads();
        red[t] = ps; __syncthreads();
        if (t < 128) red[t] += red[t + 128]; __syncthreads();
        if (t < 64)  red[t] += red[t + 64];  __syncthreads();
        if (t < 32) { red[t] += red[t + 32]; pooled_s[t] = red[t] / cnt; }
        __syncthreads();
        if (t < 3) {
            float o = lin_b[t];
#pragma unroll
            for (int f2 = 0; f2 < F; ++f2) o += pooled_s[f2] * lin_w[f2 * 3 + t];
            outp[g * 3 + t] = o;
        }
    }
}

// ---------------------------------------------------------------------------
extern "C" void kernel_launch(void* const* d_in, const int* in_sizes, int n_in,
                              void* d_out, int out_size, void* d_ws, size_t ws_size,
                              hipStream_t stream) {
    const float* x      = (const float*)d_in[0];
    const int*   ei     = (const int*)d_in[1];
    const int*   batch  = (const int*)d_in[2];
    const float* W1     = (const float*)d_in[3];
    const float* b1     = (const float*)d_in[4];
    const float* gn1w   = (const float*)d_in[5];
    const float* gn1b   = (const float*)d_in[6];
    const float* gn1ms  = (const float*)d_in[7];
    const float* W2     = (const float*)d_in[8];
    const float* b2     = (const float*)d_in[9];
    const float* gn2w   = (const float*)d_in[10];
    const float* gn2b   = (const float*)d_in[11];
    const float* gn2ms  = (const float*)d_in[12];
    const float* W3     = (const float*)d_in[13];
    const float* b3     = (const float*)d_in[14];
    const float* gn3w   = (const float*)d_in[15];
    const float* gn3b   = (const float*)d_in[16];
    const float* gn3ms  = (const float*)d_in[17];
    const float* lin_w  = (const float*)d_in[18];
    const float* lin_b  = (const float*)d_in[19];
    float* out = (float*)d_out;

    const int* srcp = ei;
    const int* dstp = ei + N_EDGES;

    char* ws = (char*)d_ws;
    size_t p = 0;
    auto alloc = [&](size_t bytes) {
        size_t r = p; p += (bytes + 511) & ~(size_t)511; return r;
    };
    int*   off       = (int*)  (ws + alloc(sizeof(int) * (N_GRAPHS + 1)));
    int*   bucketCnt = (int*)  (ws + alloc(sizeof(int) * NB));
    int*   bucketOff = (int*)  (ws + alloc(sizeof(int) * (NB + 1)));
    int*   bucketCur = (int*)  (ws + alloc(sizeof(int) * NB));
    int*   rowptr    = (int*)  (ws + alloc(sizeof(int) * (N_NODES + 1)));
    float* dinv      = (float*)(ws + alloc(sizeof(float) * N_NODES));
    unsigned int* binned = (unsigned int*)(ws + alloc(sizeof(unsigned int) * N_EDGES));
    int*   csr       = (int*)  (ws + alloc(sizeof(int) * N_EDGES));
    float* A         = (float*)(ws + alloc(sizeof(float) * N_NODES * F));
    float* B         = (float*)(ws + alloc(sizeof(float) * N_NODES * F));
    (void)ws_size; (void)n_in; (void)in_sizes; (void)out_size;

    const int TB = 256;
    dim3 blk(TB);
    int ngrid = (N_NODES + TB - 1) / TB;
    int ggrid = (N_NODES * 8 + TB - 1) / TB;

    // CSR build via bucketed counting sort
    k_init <<<ngrid, blk, 0, stream>>>(batch, bucketCnt, off, rowptr);
    k_bhist<<<NEB, blk, 0, stream>>>(dstp, bucketCnt);
    k_bscan<<<1, blk, 0, stream>>>(bucketCnt, bucketOff, bucketCur);
    k_bin  <<<NEB, blk, 0, stream>>>(srcp, dstp, bucketCur, binned);
    k_csr  <<<NB, blk, 0, stream>>>(binned, bucketOff, rowptr, dinv, csr);

    // layer 1: x(3w) -> y1=A ; GN in-place -> x1=A
    k_gat3 <<<ggrid, blk, 0, stream>>>(x, csr, rowptr, dinv, W1, b1, A);
    k_gn<false, false><<<N_GRAPHS, blk, 0, stream>>>(A, nullptr, off, gn1w, gn1b, gn1ms,
                                                     nullptr, nullptr, A);

    // layer 2: x1=A -> y2=B ; GN + res(A) in-place -> x2=B
    k_gat32<<<ggrid, blk, 0, stream>>>(A, csr, rowptr, dinv, W2, b2, B);
    k_gn<true, false><<<N_GRAPHS, blk, 0, stream>>>(B, A, off, gn2w, gn2b, gn2ms,
                                                    nullptr, nullptr, B);

    // layer 3: x2=B -> y3=A ; GN + res(B) + pool + linear -> out
    k_gat32<<<ggrid, blk, 0, stream>>>(B, csr, rowptr, dinv, W3, b3, A);
    k_gn<true, true><<<N_GRAPHS, blk, 0, stream>>>(A, B, off, gn3w, gn3b, gn3ms,
                                                   lin_w, lin_b, out);
}

// Round 4
// 373.152 us; speedup vs baseline: 8.7746x; 1.0782x over previous
//
#include <hip/hip_runtime.h>

#define N_NODES 150000
#define N_EDGES 2400000
#define N_GRAPHS 1024
#define F 32
#define EPSV 1e-5f

#define BS 256                                   // nodes per dst-bucket
#define NB ((N_NODES + BS - 1) / BS)             // 586 buckets
#define EB 4096                                  // edges per binning block
#define NEB ((N_EDGES + EB - 1) / EB)            // 586 blocks
#define EPT (EB / 256)                           // 16 edges per thread

// bf16 helpers (RTN-even encode; decode via shift/mask)
__device__ __forceinline__ float bflo(unsigned int u) {
    union { unsigned int i; float f; } v; v.i = u << 16; return v.f;
}
__device__ __forceinline__ float bfhi(unsigned int u) {
    union { unsigned int i; float f; } v; v.i = u & 0xffff0000u; return v.f;
}
__device__ __forceinline__ unsigned short f2bf(float f) {
    union { float f; unsigned int i; } v; v.f = f;
    unsigned int r = v.i + 0x7fff + ((v.i >> 16) & 1);
    return (unsigned short)(r >> 16);
}

// ---------------------------------------------------------------------------
// K0: per-graph start offsets from sorted batch; zero bucket histogram
// ---------------------------------------------------------------------------
__global__ void k_init(const int* __restrict__ batch, int* __restrict__ bucketCnt,
                       int* __restrict__ off, int* __restrict__ rowptr) {
    int i = blockIdx.x * blockDim.x + threadIdx.x;
    if (i >= N_NODES) return;
    if (i < NB) bucketCnt[i] = 0;
    if (i == 0) rowptr[N_NODES] = N_EDGES;
    int b = batch[i];
    if (i == 0) {
        for (int g = 0; g <= b; ++g) off[g] = 0;
    } else {
        int pb = batch[i - 1];
        for (int g = pb + 1; g <= b; ++g) off[g] = i;
    }
    if (i == N_NODES - 1) {
        for (int g = b + 1; g <= N_GRAPHS; ++g) off[g] = N_NODES;
    }
}

// ---------------------------------------------------------------------------
// K1: bucket histogram (LDS-aggregated)
// ---------------------------------------------------------------------------
__global__ __launch_bounds__(256) void k_bhist(const int* __restrict__ dst,
                                               int* __restrict__ bucketCnt) {
    __shared__ int h[NB];
    int t = threadIdx.x;
    for (int b = t; b < NB; b += 256) h[b] = 0;
    __syncthreads();
    int base = blockIdx.x * EB + t;
#pragma unroll
    for (int k = 0; k < EPT; ++k) {
        int e = base + k * 256;
        if (e < N_EDGES) atomicAdd(&h[dst[e] >> 8], 1);
    }
    __syncthreads();
    for (int b = t; b < NB; b += 256) {
        int c = h[b];
        if (c) atomicAdd(&bucketCnt[b], c);
    }
}

// ---------------------------------------------------------------------------
// K2: exclusive scan of bucket counts -> offsets + cursors
// ---------------------------------------------------------------------------
__global__ __launch_bounds__(256) void k_bscan(const int* __restrict__ bucketCnt,
                                               int* __restrict__ bucketOff,
                                               int* __restrict__ bucketCur) {
    __shared__ int sc[256];
    int t = threadIdx.x;
    int v[3];
    int s = 0;
#pragma unroll
    for (int k = 0; k < 3; ++k) {
        int i = t * 3 + k;
        v[k] = (i < NB) ? bucketCnt[i] : 0;
        s += v[k];
    }
    sc[t] = s;
    __syncthreads();
    for (int o = 1; o < 256; o <<= 1) {
        int x = (t >= o) ? sc[t - o] : 0;
        __syncthreads();
        sc[t] += x;
        __syncthreads();
    }
    int run = sc[t] - s;
#pragma unroll
    for (int k = 0; k < 3; ++k) {
        int i = t * 3 + k;
        if (i < NB) { bucketOff[i] = run; bucketCur[i] = run; }
        run += v[k];
    }
    if (t == 0) bucketOff[NB] = N_EDGES;
}

// ---------------------------------------------------------------------------
// K3: bin edges into buckets. key = (localdst << 18) | src
// ---------------------------------------------------------------------------
__global__ __launch_bounds__(256) void k_bin(const int* __restrict__ src,
                                             const int* __restrict__ dst,
                                             int* __restrict__ bucketCur,
                                             unsigned int* __restrict__ binned) {
    __shared__ int h[NB];
    __shared__ int gb[NB];
    int t = threadIdx.x;
    for (int b = t; b < NB; b += 256) h[b] = 0;
    __syncthreads();
    int base = blockIdx.x * EB + t;
    unsigned int key[EPT];
    int rk[EPT], bk[EPT];
#pragma unroll
    for (int k = 0; k < EPT; ++k) {
        int e = base + k * 256;
        if (e < N_EDGES) {
            int d = dst[e];
            int b = d >> 8;
            bk[k] = b;
            key[k] = ((unsigned int)(d & 255) << 18) | (unsigned int)src[e];
            rk[k] = atomicAdd(&h[b], 1);
        } else {
            bk[k] = -1;
        }
    }
    __syncthreads();
    for (int b = t; b < NB; b += 256) {
        int c = h[b];
        gb[b] = c ? atomicAdd(&bucketCur[b], c) : 0;
    }
    __syncthreads();
#pragma unroll
    for (int k = 0; k < EPT; ++k)
        if (bk[k] >= 0) binned[gb[bk[k]] + rk[k]] = key[k];
}

// ---------------------------------------------------------------------------
// K4: per-bucket CSR finalize: rowptr, dinv, xs = x*dinv (fused), csr fill
// ---------------------------------------------------------------------------
__global__ __launch_bounds__(256) void k_csr(const unsigned int* __restrict__ binned,
                                             const int* __restrict__ bucketOff,
                                             const float* __restrict__ x,
                                             int* __restrict__ rowptr,
                                             float* __restrict__ dinv,
                                             float* __restrict__ xs,
                                             int* __restrict__ csr) {
    __shared__ int lcnt[256];
    __shared__ int lpre[256];
    __shared__ int sc[256];
    int b = blockIdx.x, t = threadIdx.x;
    int e0 = bucketOff[b], e1 = bucketOff[b + 1];
    lcnt[t] = 0;
    __syncthreads();
    for (int e = e0 + t; e < e1; e += 256)
        atomicAdd(&lcnt[binned[e] >> 18], 1);
    __syncthreads();
    int v = lcnt[t];
    sc[t] = v;
    __syncthreads();
    for (int o = 1; o < 256; o <<= 1) {
        int x2 = (t >= o) ? sc[t - o] : 0;
        __syncthreads();
        sc[t] += x2;
        __syncthreads();
    }
    int excl = sc[t] - v;
    lpre[t] = excl;
    int gnode = b * BS + t;
    if (gnode < N_NODES) {
        rowptr[gnode] = e0 + excl;
        float dv = rsqrtf((float)v + 1.0f);
        dinv[gnode] = dv;
        xs[gnode * 3 + 0] = x[gnode * 3 + 0] * dv;
        xs[gnode * 3 + 1] = x[gnode * 3 + 1] * dv;
        xs[gnode * 3 + 2] = x[gnode * 3 + 2] * dv;
    }
    lcnt[t] = 0;
    __syncthreads();
    for (int e = e0 + t; e < e1; e += 256) {
        unsigned int key = binned[e];
        int ld = key >> 18;
        int pos = atomicAdd(&lcnt[ld], 1);
        csr[e0 + lpre[ld] + pos] = (int)(key & 0x3FFFFu);
    }
}

// ---------------------------------------------------------------------------
// K5a: layer-1 fused aggregate(3-wide, pre-scaled xs) + transform(3->32)+bias
// 8 threads/node
// ---------------------------------------------------------------------------
__global__ __launch_bounds__(256) void k_gat3(
        const float* __restrict__ x, const float* __restrict__ xs,
        const int* __restrict__ csr, const int* __restrict__ rowptr,
        const float* __restrict__ dinv,
        const float* __restrict__ W, const float* __restrict__ bias,
        float* __restrict__ y) {
    int gid = blockIdx.x * 256 + threadIdx.x;
    int n = gid >> 3, c = gid & 7;
    if (n >= N_NODES) return;
    float z0 = 0.f, z1 = 0.f, z2 = 0.f;
    int e0 = rowptr[n], e1 = rowptr[n + 1];
    for (int e = e0; e < e1; ++e) {
        int s = csr[e];
        z0 += xs[s * 3 + 0];
        z1 += xs[s * 3 + 1];
        z2 += xs[s * 3 + 2];
    }
    float dd = dinv[n];
    float sl = dd * dd;
    z0 = z0 * dd + sl * x[n * 3 + 0];
    z1 = z1 * dd + sl * x[n * 3 + 1];
    z2 = z2 * dd + sl * x[n * 3 + 2];
    float4 w0 = ((const float4*)(W + 0 * F))[c];
    float4 w1 = ((const float4*)(W + 1 * F))[c];
    float4 w2 = ((const float4*)(W + 2 * F))[c];
    float4 o  = ((const float4*)bias)[c];
    o.x += z0 * w0.x + z1 * w1.x + z2 * w2.x;
    o.y += z0 * w0.y + z1 * w1.y + z2 * w2.y;
    o.z += z0 * w0.z + z1 * w1.z + z2 * w2.z;
    o.w += z0 * w0.w + z1 * w1.w + z2 * w2.w;
    ((float4*)y)[n * 8 + c] = o;
}

// ---------------------------------------------------------------------------
// K5b: fused aggregate(32-wide, bf16 pre-scaled rows) + transform(32->32).
// 4 threads/node, 16B bf16 loads (8 features/thread), 2x-unrolled edge loop.
// ---------------------------------------------------------------------------
__global__ __launch_bounds__(256) void k_gat32(
        const float* __restrict__ x, const unsigned short* __restrict__ xh,
        const int* __restrict__ csr, const int* __restrict__ rowptr,
        const float* __restrict__ dinv,
        const float* __restrict__ W, const float* __restrict__ bias,
        float* __restrict__ y) {
    __shared__ float Ws[F * F];     // 4 KB
    __shared__ float bs[F];
    __shared__ float Zs[64 * 36];   // 64 local nodes, padded stride (9 KB)
    int t = threadIdx.x;
    ((float4*)Ws)[t] = ((const float4*)W)[t];
    if (t < F) bs[t] = bias[t];
    __syncthreads();

    int gid = blockIdx.x * 256 + t;
    int n = gid >> 2, c = gid & 3, ln = t >> 2;
    float acc[8] = {0.f, 0.f, 0.f, 0.f, 0.f, 0.f, 0.f, 0.f};
    if (n < N_NODES) {
        const uint4* xr = (const uint4*)xh;  // row = 4 x 16B
        int e0 = rowptr[n], e1 = rowptr[n + 1];
        int e = e0;
        for (; e + 1 < e1; e += 2) {
            int s0 = csr[e], s1 = csr[e + 1];
            uint4 u0 = xr[s0 * 4 + c];
            uint4 u1 = xr[s1 * 4 + c];
            acc[0] += bflo(u0.x); acc[1] += bfhi(u0.x);
            acc[2] += bflo(u0.y); acc[3] += bfhi(u0.y);
            acc[4] += bflo(u0.z); acc[5] += bfhi(u0.z);
            acc[6] += bflo(u0.w); acc[7] += bfhi(u0.w);
            acc[0] += bflo(u1.x); acc[1] += bfhi(u1.x);
            acc[2] += bflo(u1.y); acc[3] += bfhi(u1.y);
            acc[4] += bflo(u1.z); acc[5] += bfhi(u1.z);
            acc[6] += bflo(u1.w); acc[7] += bfhi(u1.w);
        }
        if (e < e1) {
            int s0 = csr[e];
            uint4 u0 = xr[s0 * 4 + c];
            acc[0] += bflo(u0.x); acc[1] += bfhi(u0.x);
            acc[2] += bflo(u0.y); acc[3] += bfhi(u0.y);
            acc[4] += bflo(u0.z); acc[5] += bfhi(u0.z);
            acc[6] += bflo(u0.w); acc[7] += bfhi(u0.w);
        }
        float dd = dinv[n];
        float sl = dd * dd;
        float4 s0 = ((const float4*)x)[n * 8 + c * 2];
        float4 s1 = ((const float4*)x)[n * 8 + c * 2 + 1];
        acc[0] = acc[0] * dd + sl * s0.x;
        acc[1] = acc[1] * dd + sl * s0.y;
        acc[2] = acc[2] * dd + sl * s0.z;
        acc[3] = acc[3] * dd + sl * s0.w;
        acc[4] = acc[4] * dd + sl * s1.x;
        acc[5] = acc[5] * dd + sl * s1.y;
        acc[6] = acc[6] * dd + sl * s1.z;
        acc[7] = acc[7] * dd + sl * s1.w;
    }
    *(float4*)&Zs[ln * 36 + c * 8]     = *(float4*)&acc[0];
    *(float4*)&Zs[ln * 36 + c * 8 + 4] = *(float4*)&acc[4];
    __syncthreads();

    if (n < N_NODES) {
        const float* zrow = &Zs[ln * 36];
        float4 o0 = ((const float4*)bs)[c * 2];
        float4 o1 = ((const float4*)bs)[c * 2 + 1];
#pragma unroll
        for (int k = 0; k < F; ++k) {
            float zk = zrow[k];
            float4 w0 = ((const float4*)&Ws[k * F])[c * 2];
            float4 w1 = ((const float4*)&Ws[k * F])[c * 2 + 1];
            o0.x += zk * w0.x; o0.y += zk * w0.y; o0.z += zk * w0.z; o0.w += zk * w0.w;
            o1.x += zk * w1.x; o1.y += zk * w1.y; o1.z += zk * w1.z; o1.w += zk * w1.w;
        }
        ((float4*)y)[n * 8 + c * 2]     = o0;
        ((float4*)y)[n * 8 + c * 2 + 1] = o1;
    }
}

// ---------------------------------------------------------------------------
// K6: GraphNorm (+ residual + ReLU), block per graph; in-place capable.
// WBF: also emit bf16 dinv-pre-scaled copy for the next layer's gather.
// FINAL: fuse mean-pool + 32x3 linear.
// ---------------------------------------------------------------------------
template <bool RES, bool FINAL, bool WBF>
__global__ __launch_bounds__(256) void k_gn(
        const float* agg, const float* res, const int* __restrict__ off,
        const float* __restrict__ gw, const float* __restrict__ gb,
        const float* __restrict__ gms,
        const float* __restrict__ lin_w, const float* __restrict__ lin_b,
        const float* __restrict__ dinv, unsigned short* __restrict__ xh,
        float* outp) {
    __shared__ float red[256];
    __shared__ float mean_s[F], rstd_s[F], pooled_s[F];
    int g = blockIdx.x;
    int i0 = off[g], i1 = off[g + 1];
    float cnt = (float)(i1 - i0);
    int t = threadIdx.x;
    int f = t & 31, r0 = t >> 5;
    float w = gw[f], bb = gb[f], ms = gms[f];

    float s = 0.f;
    for (int n = i0 + r0; n < i1; n += 8) s += agg[n * F + f];
    red[t] = s; __syncthreads();
    if (t < 128) red[t] += red[t + 128]; __syncthreads();
    if (t < 64)  red[t] += red[t + 64];  __syncthreads();
    if (t < 32) { red[t] += red[t + 32]; mean_s[t] = red[t] / cnt; }
    __syncthreads();

    float sq = 0.f;
    for (int n = i0 + r0; n < i1; n += 8) {
        float c = agg[n * F + f] - ms * mean_s[f];
        sq += c * c;
    }
    red[t] = sq; __syncthreads();
    if (t < 128) red[t] += red[t + 128]; __syncthreads();
    if (t < 64)  red[t] += red[t + 64];  __syncthreads();
    if (t < 32) { red[t] += red[t + 32]; rstd_s[t] = rsqrtf(red[t] / cnt + EPSV); }
    __syncthreads();

    float ps = 0.f;
    for (int n = i0 + r0; n < i1; n += 8) {
        float c = agg[n * F + f] - ms * mean_s[f];
        float y = w * c * rstd_s[f] + bb;
        if (RES) y += res[n * F + f];
        y = fmaxf(y, 0.f);
        if (!FINAL) {
            outp[n * F + f] = y;
            if (WBF) xh[n * F + f] = f2bf(y * dinv[n]);
        } else {
            ps += y;
        }
    }
    if (FINAL) {
        __syncthreads();
        red[t] = ps; __syncthreads();
        if (t < 128) red[t] += red[t + 128]; __syncthreads();
        if (t < 64)  red[t] += red[t + 64];  __syncthreads();
        if (t < 32) { red[t] += red[t + 32]; pooled_s[t] = red[t] / cnt; }
        __syncthreads();
        if (t < 3) {
            float o = lin_b[t];
#pragma unroll
            for (int f2 = 0; f2 < F; ++f2) o += pooled_s[f2] * lin_w[f2 * 3 + t];
            outp[g * 3 + t] = o;
        }
    }
}

// ---------------------------------------------------------------------------
extern "C" void kernel_launch(void* const* d_in, const int* in_sizes, int n_in,
                              void* d_out, int out_size, void* d_ws, size_t ws_size,
                              hipStream_t stream) {
    const float* x      = (const float*)d_in[0];
    const int*   ei     = (const int*)d_in[1];
    const int*   batch  = (const int*)d_in[2];
    const float* W1     = (const float*)d_in[3];
    const float* b1     = (const float*)d_in[4];
    const float* gn1w   = (const float*)d_in[5];
    const float* gn1b   = (const float*)d_in[6];
    const float* gn1ms  = (const float*)d_in[7];
    const float* W2     = (const float*)d_in[8];
    const float* b2     = (const float*)d_in[9];
    const float* gn2w   = (const float*)d_in[10];
    const float* gn2b   = (const float*)d_in[11];
    const float* gn2ms  = (const float*)d_in[12];
    const float* W3     = (const float*)d_in[13];
    const float* b3     = (const float*)d_in[14];
    const float* gn3w   = (const float*)d_in[15];
    const float* gn3b   = (const float*)d_in[16];
    const float* gn3ms  = (const float*)d_in[17];
    const float* lin_w  = (const float*)d_in[18];
    const float* lin_b  = (const float*)d_in[19];
    float* out = (float*)d_out;

    const int* srcp = ei;
    const int* dstp = ei + N_EDGES;

    char* ws = (char*)d_ws;
    size_t p = 0;
    auto alloc = [&](size_t bytes) {
        size_t r = p; p += (bytes + 511) & ~(size_t)511; return r;
    };
    int*   off       = (int*)  (ws + alloc(sizeof(int) * (N_GRAPHS + 1)));
    int*   bucketCnt = (int*)  (ws + alloc(sizeof(int) * NB));
    int*   bucketOff = (int*)  (ws + alloc(sizeof(int) * (NB + 1)));
    int*   bucketCur = (int*)  (ws + alloc(sizeof(int) * NB));
    int*   rowptr    = (int*)  (ws + alloc(sizeof(int) * (N_NODES + 1)));
    float* dinv      = (float*)(ws + alloc(sizeof(float) * N_NODES));
    float* xs        = (float*)(ws + alloc(sizeof(float) * N_NODES * 3));
    unsigned int* binned = (unsigned int*)(ws + alloc(sizeof(unsigned int) * N_EDGES));
    int*   csr       = (int*)  (ws + alloc(sizeof(int) * N_EDGES));
    float* A         = (float*)(ws + alloc(sizeof(float) * N_NODES * F));
    float* B         = (float*)(ws + alloc(sizeof(float) * N_NODES * F));
    // xh aliases binned: binned (2.4M*4B) is dead after k_csr; xh (150k*32*2B)
    // is first written by gn1 which runs later. Both are exactly 9.6 MB.
    unsigned short* xh = (unsigned short*)binned;
    (void)ws_size; (void)n_in; (void)in_sizes; (void)out_size;

    const int TB = 256;
    dim3 blk(TB);
    int ngrid  = (N_NODES + TB - 1) / TB;
    int ggrid8 = (N_NODES * 8 + TB - 1) / TB;
    int ggrid4 = (N_NODES * 4 + TB - 1) / TB;

    // CSR build via bucketed counting sort (+ dinv, xs fused into k_csr)
    k_init <<<ngrid, blk, 0, stream>>>(batch, bucketCnt, off, rowptr);
    k_bhist<<<NEB, blk, 0, stream>>>(dstp, bucketCnt);
    k_bscan<<<1, blk, 0, stream>>>(bucketCnt, bucketOff, bucketCur);
    k_bin  <<<NEB, blk, 0, stream>>>(srcp, dstp, bucketCur, binned);
    k_csr  <<<NB, blk, 0, stream>>>(binned, bucketOff, x, rowptr, dinv, xs, csr);

    // layer 1: x(3w) -> y1=A ; GN in-place -> x1=A (+ bf16 xh)
    k_gat3 <<<ggrid8, blk, 0, stream>>>(x, xs, csr, rowptr, dinv, W1, b1, A);
    k_gn<false, false, true><<<N_GRAPHS, blk, 0, stream>>>(
        A, nullptr, off, gn1w, gn1b, gn1ms, nullptr, nullptr, dinv, xh, A);

    // layer 2: (A fp32 self, xh bf16 gather) -> y2=B ; GN + res(A) -> x2=B (+ xh)
    k_gat32<<<ggrid4, blk, 0, stream>>>(A, xh, csr, rowptr, dinv, W2, b2, B);
    k_gn<true, false, true><<<N_GRAPHS, blk, 0, stream>>>(
        B, A, off, gn2w, gn2b, gn2ms, nullptr, nullptr, dinv, xh, B);

    // layer 3: (B fp32 self, xh bf16 gather) -> y3=A ; GN + res(B) + pool + linear
    k_gat32<<<ggrid4, blk, 0, stream>>>(B, xh, csr, rowptr, dinv, W3, b3, A);
    k_gn<true, true, false><<<N_GRAPHS, blk, 0, stream>>>(
        A, B, off, gn3w, gn3b, gn3ms, lin_w, lin_b, dinv, nullptr, out);
}